// Round 1
// baseline (318.756 us; speedup 1.0000x reference)
//
#include <hip/hip_runtime.h>

// RelScaleAttend: b=4, 16 heads, s=1024 (32x32 image), d=64.
// Kernel 1 (relpre): exact fp32 rel_h/rel_w dot tables -> d_ws (16 MB).
//   (fp32 required: rel terms dominate S (std~8, unscaled); bf16 here would
//    perturb the peaked softmax beyond the 0.095 abs threshold.)
// Kernel 2 (attn): flash attention, bf16 MFMA 16x16x32, fp32 accum.
//   block=256 (4 waves) <-> (bh, 2 image rows); wave owns 16 queries.
//   K-tile = 32 keys = one image row => kh == tile idx, rel_w tile-invariant.

#define BH_TOT 64          // 4 batches * 16 heads
#define SCALE  0.125f      // 64^-0.5

typedef float          f32x4  __attribute__((ext_vector_type(4)));
typedef __bf16         bf16x8 __attribute__((ext_vector_type(8)));
typedef unsigned short u16x8  __attribute__((ext_vector_type(8)));
typedef unsigned short u16x4  __attribute__((ext_vector_type(4)));

__device__ __forceinline__ unsigned short f2bf(float x) {
    unsigned u = __builtin_bit_cast(unsigned, x);
    u = (u + 0x7fffu + ((u >> 16) & 1u)) >> 16;   // RNE
    return (unsigned short)u;
}

// ---------------- kernel 1: rel tables, exact fp32 ----------------
// relh[bh][sq][kh] = sum_c q[bb,sq,nh*64+c] * rph[(sq>>5)-kh+31][c]
// relw[bh][sq][kw] = sum_c q[bb,sq,nh*64+c] * rpw[(sq&31)-kw+31][c]
__global__ __launch_bounds__(256) void relpre(
        const float* __restrict__ q,
        const float* __restrict__ rph, const float* __restrict__ rpw,
        float* __restrict__ relh, float* __restrict__ relw) {
    int g  = blockIdx.x * 256 + threadIdx.x;     // 64*1024*64 threads
    int o  = g & 63;                             // lane: 0..31 H, 32..63 W
    int sq = (g >> 6) & 1023;
    int bh = g >> 16;
    int bb = bh >> 4, nh = bh & 15;
    const float* qp = q + (size_t)bb * 1048576 + (size_t)sq * 1024 + nh * 64;
    int isw = o >> 5;
    int kx  = o & 31;
    int row = isw ? ((sq & 31) - kx + 31) : ((sq >> 5) - kx + 31);  // in [0,62]
    const float* tp = (isw ? rpw : rph) + row * 64;
    float acc = 0.f;
#pragma unroll
    for (int cq = 0; cq < 16; ++cq) {
        f32x4 a = *(const f32x4*)(qp + cq * 4);
        f32x4 b = *(const f32x4*)(tp + cq * 4);
        acc += a.x * b.x + a.y * b.y + a.z * b.z + a.w * b.w;
    }
    float* outp = isw ? relw : relh;
    outp[((bh * 1024 + sq) << 5) + kx] = acc;
}

// ---------------- kernel 2: flash attention, bf16 MFMA ----------------
__global__ __launch_bounds__(256, 2) void attn(
        const float* __restrict__ qg, const float* __restrict__ kg,
        const float* __restrict__ vg,
        const float* __restrict__ relh, const float* __restrict__ relw,
        float* __restrict__ outg) {
    // LDS: K row-major bf16 stride 72 (2-way-free b128 reads);
    //      V transposed   stride 36 (b64 reads, 4-way b32 writes);
    //      P per-wave     stride 40 (b128-aligned A-frag reads).
    __shared__ unsigned short Kl[32 * 72];
    __shared__ unsigned short Vl[64 * 36];
    __shared__ unsigned short Pl[4 * 16 * 40];

    const int tid  = threadIdx.x;
    const int w    = tid >> 6, lane = tid & 63;
    const int quad = lane >> 4, n16 = lane & 15;
    const int hp = blockIdx.x, bh = blockIdx.y;
    const int bb = bh >> 4, nh = bh & 15;
    const int h0 = hp << 1;
    const int base = bb * 1048576 + nh * 64;     // per-head element base

    // ---- Q A-fragments (once): A[m=lane&15][k=quad*8+j], two c-halves ----
    const int hq  = h0 + (w >> 1);
    const int sqa = hq * 32 + ((w & 1) << 4) + n16;     // A-layout row
    bf16x8 qf[2];
    {
        const float* qp = qg + base + sqa * 1024 + quad * 8;
#pragma unroll
        for (int ch = 0; ch < 2; ++ch) {
            f32x4 a = *(const f32x4*)(qp + ch * 32);
            f32x4 b = *(const f32x4*)(qp + ch * 32 + 4);
            u16x8 u;
            u[0] = f2bf(a.x); u[1] = f2bf(a.y); u[2] = f2bf(a.z); u[3] = f2bf(a.w);
            u[4] = f2bf(b.x); u[5] = f2bf(b.y); u[6] = f2bf(b.z); u[7] = f2bf(b.w);
            qf[ch] = __builtin_bit_cast(bf16x8, u);
        }
    }

    // C/D-layout rows this lane owns: row = quad*4 + r
    int sqr[4];
#pragma unroll
    for (int r = 0; r < 4; ++r)
        sqr[r] = hq * 32 + ((w & 1) << 4) + quad * 4 + r;

    // rel_w is tile-invariant (kw == kk within every tile): keep in regs
    float rw0[4], rw1[4];
#pragma unroll
    for (int r = 0; r < 4; ++r) {
        rw0[r] = relw[((bh * 1024 + sqr[r]) << 5) + n16];
        rw1[r] = relw[((bh * 1024 + sqr[r]) << 5) + 16 + n16];
    }

    float mr[4] = {-1e30f, -1e30f, -1e30f, -1e30f};
    float lr[4] = {0.f, 0.f, 0.f, 0.f};
    f32x4 oc[4];
#pragma unroll
    for (int i = 0; i < 4; ++i) oc[i] = (f32x4){0.f, 0.f, 0.f, 0.f};

    const int skk = tid >> 3, sc0 = (tid & 7) << 3;   // K staging coords
    const int vc  = tid & 63, vgr = tid >> 6;         // V staging coords
    const int pbase = w * 640;                        // per-wave P region

    for (int kt = 0; kt < 32; ++kt) {
        __syncthreads();
        {   // stage K tile (row kk, 8 cols) -> bf16 b128 write
            const float* kp = kg + base + (kt * 32 + skk) * 1024 + sc0;
            f32x4 a = *(const f32x4*)kp;
            f32x4 b = *(const f32x4*)(kp + 4);
            u16x8 u;
            u[0] = f2bf(a.x); u[1] = f2bf(a.y); u[2] = f2bf(a.z); u[3] = f2bf(a.w);
            u[4] = f2bf(b.x); u[5] = f2bf(b.y); u[6] = f2bf(b.z); u[7] = f2bf(b.w);
            *(u16x8*)&Kl[skk * 72 + sc0] = u;
        }
        // stage V transposed: V^T[c][kk], packed pairs along kk (b32 writes)
#pragma unroll
        for (int j = 0; j < 4; ++j) {
            int kk = ((vgr << 2) + j) << 1;
            float x = vg[base + (kt * 32 + kk) * 1024 + vc];
            float y = vg[base + (kt * 32 + kk + 1) * 1024 + vc];
            unsigned pk = (unsigned)f2bf(x) | ((unsigned)f2bf(y) << 16);
            *(unsigned*)&Vl[vc * 36 + kk] = pk;
        }
        __syncthreads();

        float rh[4];
#pragma unroll
        for (int r = 0; r < 4; ++r)
            rh[r] = relh[((bh * 1024 + sqr[r]) << 5) + kt];

        // ---- S = Q K^T : 4 MFMAs (2 col-halves x 2 k-halves) ----
        f32x4 s0 = {0.f, 0.f, 0.f, 0.f}, s1 = s0;
#pragma unroll
        for (int ch = 0; ch < 2; ++ch) {
            bf16x8 k0 = __builtin_bit_cast(bf16x8,
                *(const u16x8*)&Kl[n16 * 72 + ch * 32 + quad * 8]);
            bf16x8 k1 = __builtin_bit_cast(bf16x8,
                *(const u16x8*)&Kl[(16 + n16) * 72 + ch * 32 + quad * 8]);
            s0 = __builtin_amdgcn_mfma_f32_16x16x32_bf16(qf[ch], k0, s0, 0, 0, 0);
            s1 = __builtin_amdgcn_mfma_f32_16x16x32_bf16(qf[ch], k1, s1, 0, 0, 0);
        }

        // ---- bias + online softmax (rows live in contiguous 16-lane groups) ----
#pragma unroll
        for (int r = 0; r < 4; ++r) {
            float x0 = s0[r] * SCALE + rh[r] + rw0[r];
            float x1 = s1[r] * SCALE + rh[r] + rw1[r];
            float tm = fmaxf(x0, x1);
            tm = fmaxf(tm, __shfl_xor(tm, 1));
            tm = fmaxf(tm, __shfl_xor(tm, 2));
            tm = fmaxf(tm, __shfl_xor(tm, 4));
            tm = fmaxf(tm, __shfl_xor(tm, 8));
            float mn = fmaxf(mr[r], tm);
            float al = __expf(mr[r] - mn);
            mr[r] = mn;
            float p0 = __expf(x0 - mn);
            float p1 = __expf(x1 - mn);
            float rs = p0 + p1;
            rs += __shfl_xor(rs, 1);
            rs += __shfl_xor(rs, 2);
            rs += __shfl_xor(rs, 4);
            rs += __shfl_xor(rs, 8);
            lr[r] = lr[r] * al + rs;
#pragma unroll
            for (int cn = 0; cn < 4; ++cn) oc[cn][r] *= al;
            int pr = pbase + (quad * 4 + r) * 40;
            Pl[pr + n16]      = f2bf(p0);
            Pl[pr + 16 + n16] = f2bf(p1);
        }

        // ---- O += P V : P C-layout -> A-layout via per-wave LDS ----
        bf16x8 pf = __builtin_bit_cast(bf16x8,
            *(const u16x8*)&Pl[pbase + n16 * 40 + quad * 8]);
#pragma unroll
        for (int cn = 0; cn < 4; ++cn) {
            const unsigned short* vp = &Vl[(cn * 16 + n16) * 36 + quad * 8];
            u16x4 a = *(const u16x4*)vp;
            u16x4 b = *(const u16x4*)(vp + 4);
            u16x8 u;
            u[0] = a[0]; u[1] = a[1]; u[2] = a[2]; u[3] = a[3];
            u[4] = b[0]; u[5] = b[1]; u[6] = b[2]; u[7] = b[3];
            bf16x8 vf = __builtin_bit_cast(bf16x8, u);
            oc[cn] = __builtin_amdgcn_mfma_f32_16x16x32_bf16(pf, vf, oc[cn], 0, 0, 0);
        }
    }

    // ---- epilogue: normalize, store fp32 ----
#pragma unroll
    for (int r = 0; r < 4; ++r) {
        float inv = 1.f / lr[r];
        int ob = base + sqr[r] * 1024;
        outg[ob + n16]      = oc[0][r] * inv;
        outg[ob + 16 + n16] = oc[1][r] * inv;
        outg[ob + 32 + n16] = oc[2][r] * inv;
        outg[ob + 48 + n16] = oc[3][r] * inv;
    }
}

extern "C" void kernel_launch(void* const* d_in, const int* in_sizes, int n_in,
                              void* d_out, int out_size, void* d_ws, size_t ws_size,
                              hipStream_t stream) {
    (void)in_sizes; (void)n_in; (void)out_size; (void)ws_size;
    const float* q   = (const float*)d_in[0];
    const float* k   = (const float*)d_in[1];
    const float* v   = (const float*)d_in[2];
    const float* rph = (const float*)d_in[3];
    const float* rpw = (const float*)d_in[4];
    float* relh = (float*)d_ws;                       // 64*1024*32 f32 = 8 MB
    float* relw = relh + 64 * 1024 * 32;              // + 8 MB

    relpre<<<16384, 256, 0, stream>>>(q, rph, rpw, relh, relw);
    dim3 g(16, 64);                                   // (h-pair, bh)
    attn<<<g, 256, 0, stream>>>(q, k, v, relh, relw, (float*)d_out);
}

// Round 2
// 227.912 us; speedup vs baseline: 1.3986x; 1.3986x over previous
//
#include <hip/hip_runtime.h>

// RelScaleAttend: b=4, 16 heads, s=1024 (32x32 img), d=64. Single fused kernel.
// Block = (h-pair, bh): 64 queries, 4 waves x 16 queries. K-tile = 64 keys.
// Phase 0: exact fp32 rel_h/rel_w tables (x log2e) into LDS (fp32 required:
//   rel terms dominate S, bf16 there breaks the 0.095 threshold; qk term is
//   scaled by 1/8 so bf16 MFMA is safe).
// Phase 1: flash attention, bf16 MFMA 16x16x32, fp32 accum, exp2-domain
//   online softmax.

#define SCALE2 0.18033688f   // 0.125 * log2(e)
#define LOG2E  1.44269504f

typedef float  f32x4  __attribute__((ext_vector_type(4)));
typedef __bf16 bf16x8 __attribute__((ext_vector_type(8)));
typedef __bf16 bf16x4 __attribute__((ext_vector_type(4)));
typedef __bf16 bf16x2 __attribute__((ext_vector_type(2)));

__global__ __launch_bounds__(256, 3) void attn(
        const float* __restrict__ qg, const float* __restrict__ kg,
        const float* __restrict__ vg,
        const float* __restrict__ rph, const float* __restrict__ rpw,
        float* __restrict__ outg) {
    // LDS plan (44544 B total -> 3 blocks/CU):
    //   RelH/RelW: 64 x 34 f32 (stride 34: conflict-free scalar stores,
    //              aligned b64 row-pair reads)
    //   arena: phase0 = Ql 64x68 f32 (17408 B; b128 reads at 8-phase optimum)
    //          phase1 = Kl 64x72 bf16 + Vl 64x68 bf16 + Pl 4x16x72 bf16
    __shared__ float RelH[64 * 34];
    __shared__ float RelW[64 * 34];
    __shared__ __align__(16) char arena[27136];
    float*  Ql = (float*)arena;
    __bf16* Kl = (__bf16*)arena;            // 64*72 = 9216 B
    __bf16* Vl = Kl + 64 * 72;              // 64*68 = 8704 B
    __bf16* Pl = Vl + 64 * 68;              // 4*16*72 = 9216 B

    const int tid  = threadIdx.x;
    const int w    = tid >> 6, lane = tid & 63;
    const int quad = lane >> 4, n16 = lane & 15;
    const int hp = blockIdx.x, bh = blockIdx.y;
    const int bb = bh >> 4, nh = bh & 15;
    const int h0 = hp << 1;
    const int base = bb * 1048576 + nh * 64;   // per-head element base
    const int sq0  = h0 * 32;                  // first query row of block

    // ---- stage Q rows (fp32) into LDS, fully coalesced (1 KB/instr) ----
    {
        int r0 = tid >> 4, c0 = (tid & 15) << 2;
#pragma unroll
        for (int k = 0; k < 4; ++k) {
            int row = k * 16 + r0;
            f32x4 v = *(const f32x4*)(qg + base + (sq0 + row) * 1024 + c0);
            *(f32x4*)&Ql[row * 68 + c0] = v;
        }
    }
    __syncthreads();

    // ---- phase 0: rel tables (pre-scaled by log2e) ----
    {
        int ql = tid & 63, slot = tid >> 6;
        int isw = slot >> 1, khb = (slot & 1) << 4;
        int hh = h0 + (ql >> 5), wl = ql & 31;
        int row0 = (isw ? wl : hh) + 31 - khb;      // row for j=0; row_j = row0-j
        const float* tp = (isw ? rpw : rph) + row0 * 64;
        const float* qrow = &Ql[ql * 68];
        float acc[16];
#pragma unroll
        for (int j = 0; j < 16; ++j) acc[j] = 0.f;
#pragma unroll 4
        for (int cq = 0; cq < 16; ++cq) {
            f32x4 qv = *(const f32x4*)(qrow + cq * 4);
#pragma unroll
            for (int j = 0; j < 16; ++j) {
                f32x4 tv = *(const f32x4*)(tp - j * 64 + cq * 4);
                acc[j] += qv.x * tv.x + qv.y * tv.y + qv.z * tv.z + qv.w * tv.w;
            }
        }
        float* dst = (isw ? RelW : RelH) + ql * 34 + khb;
#pragma unroll
        for (int j = 0; j < 16; ++j) dst[j] = acc[j] * LOG2E;
    }

    // ---- Q A-fragments from Ql: A[m=n16][k=quad*8+j], query = w*16+n16 ----
    const int qla = w * 16 + n16;
    bf16x8 qf[2];
#pragma unroll
    for (int ch = 0; ch < 2; ++ch) {
        const float* qp = &Ql[qla * 68 + ch * 32 + quad * 8];
        f32x4 a = ((const f32x4*)qp)[0];
        f32x4 b = ((const f32x4*)qp)[1];
        bf16x8 t;
        t[0] = (__bf16)a.x; t[1] = (__bf16)a.y; t[2] = (__bf16)a.z; t[3] = (__bf16)a.w;
        t[4] = (__bf16)b.x; t[5] = (__bf16)b.y; t[6] = (__bf16)b.z; t[7] = (__bf16)b.w;
        qf[ch] = t;
    }
    __syncthreads();   // RelH/RelW ready; Ql arena now reusable as Kl/Vl/Pl

    // C/D rows this lane owns: local query = w*16 + quad*4 + r
    int qlr[4];
#pragma unroll
    for (int r = 0; r < 4; ++r) qlr[r] = w * 16 + quad * 4 + r;

    // rel_w is tile-invariant: col group g has kw = n16 + 16*(g&1)
    float rwv[4][2];
#pragma unroll
    for (int r = 0; r < 4; ++r) {
        rwv[r][0] = RelW[qlr[r] * 34 + n16];
        rwv[r][1] = RelW[qlr[r] * 34 + 16 + n16];
    }

    float mr[4] = {-1e30f, -1e30f, -1e30f, -1e30f};
    float lr[4] = {0.f, 0.f, 0.f, 0.f};
    f32x4 oc[4];
#pragma unroll
    for (int i = 0; i < 4; ++i) oc[i] = (f32x4){0.f, 0.f, 0.f, 0.f};

    const int krow = tid >> 3, kc0 = (tid & 7) << 3;   // K staging coords
    const int vc = tid & 63, vk0 = (tid >> 6) << 4;    // V staging coords
    const int pw = w * 1152;                           // per-wave P base

    for (int kt = 0; kt < 16; ++kt) {
        // ---- stage K tile (64x64) bf16 row-major, b128 writes ----
#pragma unroll
        for (int half = 0; half < 2; ++half) {
            int row = krow + half * 32;
            const float* kp = kg + base + (kt * 64 + row) * 1024 + kc0;
            f32x4 a = ((const f32x4*)kp)[0];
            f32x4 b = ((const f32x4*)kp)[1];
            bf16x8 t;
            t[0] = (__bf16)a.x; t[1] = (__bf16)a.y; t[2] = (__bf16)a.z; t[3] = (__bf16)a.w;
            t[4] = (__bf16)b.x; t[5] = (__bf16)b.y; t[6] = (__bf16)b.z; t[7] = (__bf16)b.w;
            *(bf16x8*)&Kl[row * 72 + kc0] = t;
        }
        // ---- stage V transposed: Vl[c][kk], packed pairs along kk ----
#pragma unroll
        for (int j = 0; j < 8; ++j) {
            int kk = vk0 + 2 * j;
            float x = vg[base + (kt * 64 + kk) * 1024 + vc];
            float y = vg[base + (kt * 64 + kk + 1) * 1024 + vc];
            bf16x2 p; p[0] = (__bf16)x; p[1] = (__bf16)y;
            *(bf16x2*)&Vl[vc * 68 + kk] = p;
        }
        __syncthreads();

        float rh[4][2];
#pragma unroll
        for (int r = 0; r < 4; ++r) {
            float2 t = *(const float2*)&RelH[qlr[r] * 34 + kt * 2];
            rh[r][0] = t.x; rh[r][1] = t.y;
        }

        // ---- S = Q K^T : 8 MFMAs (4 key groups x 2 c-halves) ----
        f32x4 s[4];
#pragma unroll
        for (int g = 0; g < 4; ++g) s[g] = (f32x4){0.f, 0.f, 0.f, 0.f};
#pragma unroll
        for (int ch = 0; ch < 2; ++ch)
#pragma unroll
            for (int g = 0; g < 4; ++g) {
                bf16x8 kf = *(const bf16x8*)&Kl[(g * 16 + n16) * 72 + ch * 32 + quad * 8];
                s[g] = __builtin_amdgcn_mfma_f32_16x16x32_bf16(qf[ch], kf, s[g], 0, 0, 0);
            }

        // ---- bias + online softmax (exp2 domain) ----
#pragma unroll
        for (int r = 0; r < 4; ++r) {
            float x0 = fmaf(s[0][r], SCALE2, rh[r][0] + rwv[r][0]);
            float x1 = fmaf(s[1][r], SCALE2, rh[r][0] + rwv[r][1]);
            float x2 = fmaf(s[2][r], SCALE2, rh[r][1] + rwv[r][0]);
            float x3 = fmaf(s[3][r], SCALE2, rh[r][1] + rwv[r][1]);
            float tm = fmaxf(fmaxf(x0, x1), fmaxf(x2, x3));
            tm = fmaxf(tm, __shfl_xor(tm, 1));
            tm = fmaxf(tm, __shfl_xor(tm, 2));
            tm = fmaxf(tm, __shfl_xor(tm, 4));
            tm = fmaxf(tm, __shfl_xor(tm, 8));
            float mn = fmaxf(mr[r], tm);
            float al = exp2f(mr[r] - mn);
            mr[r] = mn;
            float p0 = exp2f(x0 - mn), p1 = exp2f(x1 - mn);
            float p2 = exp2f(x2 - mn), p3 = exp2f(x3 - mn);
            float rs = (p0 + p1) + (p2 + p3);
            rs += __shfl_xor(rs, 1);
            rs += __shfl_xor(rs, 2);
            rs += __shfl_xor(rs, 4);
            rs += __shfl_xor(rs, 8);
            lr[r] = fmaf(lr[r], al, rs);
            oc[0][r] *= al; oc[1][r] *= al; oc[2][r] *= al; oc[3][r] *= al;
            int pr = pw + (quad * 4 + r) * 72;
            Pl[pr + n16]      = (__bf16)p0;
            Pl[pr + 16 + n16] = (__bf16)p1;
            Pl[pr + 32 + n16] = (__bf16)p2;
            Pl[pr + 48 + n16] = (__bf16)p3;
        }

        // ---- O += P V : P C-layout -> A-layout via per-wave LDS ----
#pragma unroll
        for (int ko = 0; ko < 2; ++ko) {
            bf16x8 pf = *(const bf16x8*)&Pl[pw + n16 * 72 + ko * 32 + quad * 8];
#pragma unroll
            for (int cn = 0; cn < 4; ++cn) {
                const __bf16* vp = &Vl[(cn * 16 + n16) * 68 + ko * 32 + quad * 8];
                bf16x4 a = *(const bf16x4*)vp;
                bf16x4 b = *(const bf16x4*)(vp + 4);
                bf16x8 vf;
                vf[0] = a[0]; vf[1] = a[1]; vf[2] = a[2]; vf[3] = a[3];
                vf[4] = b[0]; vf[5] = b[1]; vf[6] = b[2]; vf[7] = b[3];
                oc[cn] = __builtin_amdgcn_mfma_f32_16x16x32_bf16(pf, vf, oc[cn], 0, 0, 0);
            }
        }
        __syncthreads();
    }

    // ---- epilogue: normalize, store fp32 ----
#pragma unroll
    for (int r = 0; r < 4; ++r) {
        float inv = 1.f / lr[r];
        int ob = base + (sq0 + qlr[r]) * 1024 + n16;
        outg[ob]      = oc[0][r] * inv;
        outg[ob + 16] = oc[1][r] * inv;
        outg[ob + 32] = oc[2][r] * inv;
        outg[ob + 48] = oc[3][r] * inv;
    }
}

extern "C" void kernel_launch(void* const* d_in, const int* in_sizes, int n_in,
                              void* d_out, int out_size, void* d_ws, size_t ws_size,
                              hipStream_t stream) {
    (void)in_sizes; (void)n_in; (void)out_size; (void)d_ws; (void)ws_size;
    const float* q   = (const float*)d_in[0];
    const float* k   = (const float*)d_in[1];
    const float* v   = (const float*)d_in[2];
    const float* rph = (const float*)d_in[3];
    const float* rpw = (const float*)d_in[4];
    dim3 g(16, 64);                      // (h-pair, bh)
    attn<<<g, 256, 0, stream>>>(q, k, v, rph, rpw, (float*)d_out);
}

// Round 3
// 201.741 us; speedup vs baseline: 1.5800x; 1.1297x over previous
//
#include <hip/hip_runtime.h>

// RelScaleAttend: b=4, 16 heads, s=1024 (32x32 img), d=64. Single fused kernel.
// Block = (h-pair, bh): 64 queries, 4 waves x 16 queries. K-tile = 64 keys.
// Phase 0: exact fp32 rel tables (x log2e) + per-query max-bound M into LDS.
// Phase 1: flash loop, bf16 MFMA 16x16x32, fp32 accum, STATIC-max softmax:
//   p = exp2(qk*SCALE2 + relh2 + relw2 - M[q]); M = max_kh relh2 + max_kw relw2
//   bounds the true row max within +-|qk|/8*log2e (every (kh,kw) key exists),
//   so no running max / rescale / per-tile reductions are needed (exact math).
// K/V for tile kt+1 are prefetched into registers during tile kt's compute.

#define SCALE2 0.18033688f   // 0.125 * log2(e)
#define LOG2E  1.44269504f

typedef float  f32x4  __attribute__((ext_vector_type(4)));
typedef __bf16 bf16x8 __attribute__((ext_vector_type(8)));
typedef __bf16 bf16x4 __attribute__((ext_vector_type(4)));
typedef __bf16 bf16x2 __attribute__((ext_vector_type(2)));

__global__ __launch_bounds__(256, 3) void attn(
        const float* __restrict__ qg, const float* __restrict__ kg,
        const float* __restrict__ vg,
        const float* __restrict__ rph, const float* __restrict__ rpw,
        float* __restrict__ outg) {
    // LDS (~45.5 KB -> 3 blocks/CU):
    //   RelH/RelW 64x34 f32; MH[4][64] half-maxes;
    //   arena: phase0 = Ql 64x68 f32; phase1 = Kl 64x72 + Vl 64x68 + Pl 4x16x72 bf16
    __shared__ float RelH[64 * 34];
    __shared__ float RelW[64 * 34];
    __shared__ float MH[4 * 64];
    __shared__ __align__(16) char arena[27136];
    float*  Ql = (float*)arena;
    __bf16* Kl = (__bf16*)arena;            // 64*72*2 = 9216 B
    __bf16* Vl = Kl + 64 * 72;              // 64*68*2 = 8704 B
    __bf16* Pl = Vl + 64 * 68;              // 4*16*72*2 = 9216 B

    const int tid  = threadIdx.x;
    const int w    = tid >> 6, lane = tid & 63;
    const int quad = lane >> 4, n16 = lane & 15;
    const int hp = blockIdx.x, bh = blockIdx.y;
    const int bb = bh >> 4, nh = bh & 15;
    const int h0 = hp << 1;
    const int base = bb * 1048576 + nh * 64;   // per-head element base
    const int sq0  = h0 * 32;                  // first query row of block

    // ---- stage Q rows (fp32) into LDS, coalesced b128 ----
    {
        int r0 = tid >> 4, c0 = (tid & 15) << 2;
#pragma unroll
        for (int k = 0; k < 4; ++k) {
            int row = k * 16 + r0;
            f32x4 v = *(const f32x4*)(qg + base + (sq0 + row) * 1024 + c0);
            *(f32x4*)&Ql[row * 68 + c0] = v;
        }
    }
    __syncthreads();

    // ---- phase 0: rel tables (x log2e) + per-slot max ----
    {
        int ql = tid & 63, slot = tid >> 6;
        int isw = slot >> 1, khb = (slot & 1) << 4;
        int hh = h0 + (ql >> 5), wl = ql & 31;
        int row0 = (isw ? wl : hh) + 31 - khb;      // row_j = row0 - j
        const float* tp = (isw ? rpw : rph) + row0 * 64;
        const float* qrow = &Ql[ql * 68];
        float acc[16];
#pragma unroll
        for (int j = 0; j < 16; ++j) acc[j] = 0.f;
#pragma unroll 4
        for (int cq = 0; cq < 16; ++cq) {
            f32x4 qv = *(const f32x4*)(qrow + cq * 4);
#pragma unroll
            for (int j = 0; j < 16; ++j) {
                f32x4 tv = *(const f32x4*)(tp - j * 64 + cq * 4);
                acc[j] += qv.x * tv.x + qv.y * tv.y + qv.z * tv.z + qv.w * tv.w;
            }
        }
        float* dst = (isw ? RelW : RelH) + ql * 34 + khb;
        float hmax = -1e30f;
#pragma unroll
        for (int j = 0; j < 16; ++j) {
            float v = acc[j] * LOG2E;
            dst[j] = v;
            hmax = fmaxf(hmax, v);
        }
        MH[slot * 64 + ql] = hmax;
    }

    // ---- Q A-fragments from Ql: A[m=n16][k=quad*8+j], query = w*16+n16 ----
    const int qla = w * 16 + n16;
    bf16x8 qf[2];
#pragma unroll
    for (int ch = 0; ch < 2; ++ch) {
        const float* qp = &Ql[qla * 68 + ch * 32 + quad * 8];
        f32x4 a = ((const f32x4*)qp)[0];
        f32x4 b = ((const f32x4*)qp)[1];
        bf16x8 t;
        t[0] = (__bf16)a.x; t[1] = (__bf16)a.y; t[2] = (__bf16)a.z; t[3] = (__bf16)a.w;
        t[4] = (__bf16)b.x; t[5] = (__bf16)b.y; t[6] = (__bf16)b.z; t[7] = (__bf16)b.w;
        qf[ch] = t;
    }
    __syncthreads();   // Rel/MH ready; Ql consumed into qf

    // C/D rows this lane owns: local query = w*16 + quad*4 + r
    int qlr[4];
#pragma unroll
    for (int r = 0; r < 4; ++r) qlr[r] = w * 16 + quad * 4 + r;

    // per-row static max M and (rel_w - M); rel_w is tile-invariant
    float rwm[4][2];
#pragma unroll
    for (int r = 0; r < 4; ++r) {
        int q = qlr[r];
        float M = fmaxf(MH[q], MH[64 + q]) + fmaxf(MH[128 + q], MH[192 + q]);
        rwm[r][0] = RelW[q * 34 + n16] - M;
        rwm[r][1] = RelW[q * 34 + 16 + n16] - M;
    }

    float lr[4] = {0.f, 0.f, 0.f, 0.f};
    f32x4 oc[4];
#pragma unroll
    for (int i = 0; i < 4; ++i) oc[i] = (f32x4){0.f, 0.f, 0.f, 0.f};

    const int krow = tid >> 3, kc0 = (tid & 7) << 3;   // K staging coords
    const int vc = tid & 63, vk0 = (tid >> 6) << 4;    // V staging coords
    const int pw = w * 1152;                           // per-wave P base

    // ---- register prefetch of tile 0 ----
    f32x4 ka[2], kb[2];
    float vv[16];
#pragma unroll
    for (int half = 0; half < 2; ++half) {
        const float* kp = kg + base + (krow + half * 32) * 1024 + kc0;
        ka[half] = ((const f32x4*)kp)[0];
        kb[half] = ((const f32x4*)kp)[1];
    }
#pragma unroll
    for (int j = 0; j < 16; ++j)
        vv[j] = vg[base + (vk0 + j) * 1024 + vc];

    for (int kt = 0; kt < 16; ++kt) {
        __syncthreads();   // previous iter's LDS reads done
        // ---- store prefetched K tile (bf16, b128 writes) ----
#pragma unroll
        for (int half = 0; half < 2; ++half) {
            bf16x8 t;
            t[0] = (__bf16)ka[half].x; t[1] = (__bf16)ka[half].y;
            t[2] = (__bf16)ka[half].z; t[3] = (__bf16)ka[half].w;
            t[4] = (__bf16)kb[half].x; t[5] = (__bf16)kb[half].y;
            t[6] = (__bf16)kb[half].z; t[7] = (__bf16)kb[half].w;
            *(bf16x8*)&Kl[(krow + half * 32) * 72 + kc0] = t;
        }
        // ---- store prefetched V transposed: Vl[c][kk], packed pairs ----
#pragma unroll
        for (int j = 0; j < 8; ++j) {
            bf16x2 p; p[0] = (__bf16)vv[2 * j]; p[1] = (__bf16)vv[2 * j + 1];
            *(bf16x2*)&Vl[vc * 68 + vk0 + 2 * j] = p;
        }
        __syncthreads();

        // ---- issue global loads for tile kt+1 (overlap with compute) ----
        if (kt < 15) {
#pragma unroll
            for (int half = 0; half < 2; ++half) {
                const float* kp = kg + base + ((kt + 1) * 64 + krow + half * 32) * 1024 + kc0;
                ka[half] = ((const f32x4*)kp)[0];
                kb[half] = ((const f32x4*)kp)[1];
            }
#pragma unroll
            for (int j = 0; j < 16; ++j)
                vv[j] = vg[base + ((kt + 1) * 64 + vk0 + j) * 1024 + vc];
        }

        float rh[4][2];
#pragma unroll
        for (int r = 0; r < 4; ++r) {
            float2 t = *(const float2*)&RelH[qlr[r] * 34 + kt * 2];
            rh[r][0] = t.x; rh[r][1] = t.y;
        }

        // ---- S = Q K^T : 8 MFMAs ----
        f32x4 s[4];
#pragma unroll
        for (int g = 0; g < 4; ++g) s[g] = (f32x4){0.f, 0.f, 0.f, 0.f};
#pragma unroll
        for (int ch = 0; ch < 2; ++ch)
#pragma unroll
            for (int g = 0; g < 4; ++g) {
                bf16x8 kf = *(const bf16x8*)&Kl[(g * 16 + n16) * 72 + ch * 32 + quad * 8];
                s[g] = __builtin_amdgcn_mfma_f32_16x16x32_bf16(qf[ch], kf, s[g], 0, 0, 0);
            }

        // ---- static-max softmax: p = exp2(s*SCALE2 + rh + rw - M) ----
#pragma unroll
        for (int r = 0; r < 4; ++r) {
            float p0 = exp2f(fmaf(s[0][r], SCALE2, rh[r][0] + rwm[r][0]));
            float p1 = exp2f(fmaf(s[1][r], SCALE2, rh[r][0] + rwm[r][1]));
            float p2 = exp2f(fmaf(s[2][r], SCALE2, rh[r][1] + rwm[r][0]));
            float p3 = exp2f(fmaf(s[3][r], SCALE2, rh[r][1] + rwm[r][1]));
            lr[r] += (p0 + p1) + (p2 + p3);
            int pr = pw + (quad * 4 + r) * 72;
            Pl[pr + n16]      = (__bf16)p0;
            Pl[pr + 16 + n16] = (__bf16)p1;
            Pl[pr + 32 + n16] = (__bf16)p2;
            Pl[pr + 48 + n16] = (__bf16)p3;
        }

        // ---- O += P V ----
#pragma unroll
        for (int ko = 0; ko < 2; ++ko) {
            bf16x8 pf = *(const bf16x8*)&Pl[pw + n16 * 72 + ko * 32 + quad * 8];
#pragma unroll
            for (int cn = 0; cn < 4; ++cn) {
                const __bf16* vp = &Vl[(cn * 16 + n16) * 68 + ko * 32 + quad * 8];
                bf16x4 a = *(const bf16x4*)vp;
                bf16x4 b = *(const bf16x4*)(vp + 4);
                bf16x8 vf;
                vf[0] = a[0]; vf[1] = a[1]; vf[2] = a[2]; vf[3] = a[3];
                vf[4] = b[0]; vf[5] = b[1]; vf[6] = b[2]; vf[7] = b[3];
                oc[cn] = __builtin_amdgcn_mfma_f32_16x16x32_bf16(pf, vf, oc[cn], 0, 0, 0);
            }
        }
    }

    // ---- epilogue: one l-reduction across the 16-lane row group, store ----
#pragma unroll
    for (int r = 0; r < 4; ++r) {
        float l = lr[r];
        l += __shfl_xor(l, 1);
        l += __shfl_xor(l, 2);
        l += __shfl_xor(l, 4);
        l += __shfl_xor(l, 8);
        float inv = 1.f / l;
        int ob = base + (sq0 + qlr[r]) * 1024 + n16;
        outg[ob]      = oc[0][r] * inv;
        outg[ob + 16] = oc[1][r] * inv;
        outg[ob + 32] = oc[2][r] * inv;
        outg[ob + 48] = oc[3][r] * inv;
    }
}

extern "C" void kernel_launch(void* const* d_in, const int* in_sizes, int n_in,
                              void* d_out, int out_size, void* d_ws, size_t ws_size,
                              hipStream_t stream) {
    (void)in_sizes; (void)n_in; (void)out_size; (void)d_ws; (void)ws_size;
    const float* q   = (const float*)d_in[0];
    const float* k   = (const float*)d_in[1];
    const float* v   = (const float*)d_in[2];
    const float* rph = (const float*)d_in[3];
    const float* rpw = (const float*)d_in[4];
    dim3 g(16, 64);                      // (h-pair, bh)
    attn<<<g, 256, 0, stream>>>(q, k, v, rph, rpw, (float*)d_out);
}